// Round 2
// baseline (926.838 us; speedup 1.0000x reference)
//
#include <hip/hip_runtime.h>
#include <stdint.h>

#define HID  128
#define N1   512
#define NCAT 1024
#define NTB  48      // edges per tile in the fused kernel

typedef _Float16 f16;
typedef __attribute__((ext_vector_type(8))) _Float16 f16x8;
typedef __attribute__((ext_vector_type(4))) _Float16 f16x4;
typedef __attribute__((ext_vector_type(8))) short   short8;
typedef __attribute__((ext_vector_type(4))) float   floatx4;
typedef __attribute__((ext_vector_type(2))) float   floatx2;
typedef __attribute__((ext_vector_type(8))) __bf16  bf16x8;

static __device__ __forceinline__ short f2bf(float x) {
  uint32_t u = __builtin_bit_cast(uint32_t, x);
  uint32_t r = (u + 0x7FFFu + ((u >> 16) & 1u)) >> 16;
  return (short)r;
}
static __device__ __forceinline__ float bf2f(short s) {
  uint32_t u = ((uint32_t)(uint16_t)s) << 16;
  return __builtin_bit_cast(float, u);
}

// async global->LDS, 16B per lane. Global source address is per-lane
// (scatter/gather OK); LDS dest is wave-uniform base + lane*16.
static __device__ __forceinline__ void gload16(const f16* g, f16* l) {
  __builtin_amdgcn_global_load_lds(
      (const __attribute__((address_space(1))) unsigned int*)g,
      (__attribute__((address_space(3))) unsigned int*)l, 16, 0, 0);
}

// ---------------- tier-1 (fused fp16 MFMA) ----------------

// prep: A' = relu(feats) as f16 (n_nodes,128); BT2[n][k] = W1[k][n] f16,
// n in [0,512), k in [0,256) (K = concat dim: k<128 -> u-features).
__global__ __launch_bounds__(256) void prep_all(
    const float* __restrict__ feats, const float* __restrict__ W1,
    f16* __restrict__ A, f16* __restrict__ BT2, int total4) {
  int idx = blockIdx.x * 256 + threadIdx.x;
  if (idx < total4) {
    floatx4 f = *(const floatx4*)(feats + (size_t)idx * 4);
    f16x4 o;
#pragma unroll
    for (int j = 0; j < 4; ++j) o[j] = (f16)fmaxf(f[j], 0.f);
    *(f16x4*)(A + (size_t)idx * 4) = o;
    return;
  }
  int w = idx - total4;
  if (w < N1 * 256) {
    int n = w >> 8;
    int k = w & 255;
    BT2[w] = (f16)W1[k * N1 + n];
  }
}

// Fused edge MLP, software-pipelined: MFMA of tile t is hand-interleaved
// with the VALU epilogue (relu(.+b1)@W2) of tile t-1 (double accumulator
// state, static 2-way unroll), and the global out-write of tile t-2 rides
// right after the barrier under the gather issue. MFMA and VALU are
// separate pipes (m114), so the epilogue cost hides under the MFMA burst.
__global__ __launch_bounds__(512, 2) void fused_kernel(
    const f16* __restrict__ A,      // (n_nodes,128) relu'd f16
    const f16* __restrict__ BT2,    // (512,256) f16 = W1^T
    const float* __restrict__ b1,   // (512,)
    const float* __restrict__ W2,   // (512,2)
    const float* __restrict__ b2,   // (2,)
    const int* __restrict__ edges,  // (2, n_edges) int32
    float* __restrict__ out,        // (n_edges,2)
    int n_edges, int ntiles) {
  __shared__ f16 AU[2][NTB][HID];        // 24 KB  (u half, K 0..127)
  __shared__ f16 AV[2][NTB][HID];        // 24 KB  (v half, K 128..255)
  __shared__ float   part[2][8][NTB][2]; // 6 KB   cross-wave partials (dbuf)
  __shared__ float   b1s[N1];            // 2 KB
  __shared__ floatx2 w2s[N1];            // 4 KB   (W2[n][0],W2[n][1]) pairs

  const int tid  = threadIdx.x;
  const int wave = tid >> 6;
  const int lane = tid & 63;
  const int quad = lane >> 4;
  const int l16  = lane & 15;
  const int n0w  = wave << 6;           // this wave's 64-col N slice

  if (tid < N1) {
    b1s[tid] = b1[tid];
    w2s[tid] = *(const floatx2*)(W2 + 2 * tid);
  }
  const float b2v0 = b2[0], b2v1 = b2[1];

  // Persistent B fragments (128 VGPR): row <-> l16, k <-> quad*8 + kk*32.
  f16x8 bfr[4][8];
#pragma unroll
  for (int nn = 0; nn < 4; ++nn) {
    const f16* bp = BT2 + (size_t)(n0w + nn * 16 + l16) * 256 + quad * 8;
#pragma unroll
    for (int kk = 0; kk < 8; ++kk) bfr[nn][kk] = *(const f16x8*)(bp + kk * 32);
  }

  // Gather geometry: 24 calls of 4 rows (64 lanes x 16B = 1KB each);
  // wave w issues calls j = 3w..3w+2.  j<12 -> AU rows 4j.., else AV.
  const int j0   = wave * 3;
  const int rsub = lane >> 4;

  int idr[3];
  auto load_idx = [&](int t) {
#pragma unroll
    for (int c = 0; c < 3; ++c) {
      int j = j0 + c;
      int side = (j >= 12) ? 1 : 0;
      int r = ((j - side * 12) << 2) + rsub;
      int e = t * NTB + r;
      if (e >= n_edges) e = n_edges - 1;
      idr[c] = edges[side * n_edges + e];
    }
  };
  // XOR-swizzle via pre-swizzled global source (m173); LDS dest linear.
  auto issue_gather = [&](int b) {
#pragma unroll
    for (int c = 0; c < 3; ++c) {
      int j = j0 + c;
      int side = (j >= 12) ? 1 : 0;
      int r0 = (j - side * 12) << 2;
      int r  = r0 + rsub;
      const f16* src = A + ((size_t)idr[c] << 7) + (((lane & 15) ^ (r & 15)) << 3);
      f16* dst = side ? &AV[b][r0][0] : &AU[b][r0][0];
      gload16(src, dst);
    }
  };

  // epilogue piece p = (mt = p>>2, nn = p&3): bias+relu+W2-dot for 4 n.
  auto piece = [&](floatx4 (&accP)[3][4], int p, float (&s0)[3], float (&s1)[3]) {
    const int mt = p >> 2, nn = p & 3;
    const int nb = n0w + nn * 16 + (quad << 2);
    const floatx4 bv  = *(const floatx4*)&b1s[nb];
    const floatx4 w01 = *(const floatx4*)&w2s[nb];      // w2[nb], w2[nb+1]
    const floatx4 w23 = *(const floatx4*)&w2s[nb + 2];  // w2[nb+2], w2[nb+3]
    float p0 = fmaxf(accP[mt][nn][0] + bv[0], 0.f);
    float p1 = fmaxf(accP[mt][nn][1] + bv[1], 0.f);
    float p2 = fmaxf(accP[mt][nn][2] + bv[2], 0.f);
    float p3 = fmaxf(accP[mt][nn][3] + bv[3], 0.f);
    s0[mt] += p0 * w01[0] + p1 * w01[2] + p2 * w23[0] + p3 * w23[2];
    s1[mt] += p0 * w01[1] + p1 * w01[3] + p2 * w23[1] + p3 * w23[3];
  };

  auto outwrite = [&](int tt, int ps) {
    const int m = tid >> 1, jj = tid & 1;
    float s = part[ps][0][m][jj] + part[ps][1][m][jj] + part[ps][2][m][jj] +
              part[ps][3][m][jj] + part[ps][4][m][jj] + part[ps][5][m][jj] +
              part[ps][6][m][jj] + part[ps][7][m][jj];
    const int e = tt * NTB + m;
    if (e < n_edges) out[2 * (size_t)e + jj] = s + (jj ? b2v1 : b2v0);
  };

  const int NB = gridDim.x;
  const int t0 = blockIdx.x;
  int bb = 0;

  if (t0 < ntiles) {
    load_idx(t0);
    issue_gather(0);
    load_idx(t0 + NB);
  }

  floatx4 accA[3][4], accB[3][4];

  // One pipeline stage: compute tile t into accC while epiloguing accP
  // (tile t-NB) inside the MFMA burst; out-write tile t-2NB up front.
  auto body = [&](floatx4 (&accC)[3][4], floatx4 (&accP)[3][4], int t, int i) {
    __syncthreads();   // gathers for t complete; part[(i+1)&1] stable

    if (t + NB < ntiles) {
      issue_gather(bb ^ 1);          // tile t+NB flies under compute
      load_idx(t + 2 * NB);
    }
    if (i >= 2 && tid < 2 * NTB) outwrite(t - 2 * NB, (i + 1) & 1);

    const bool doEpi = (i >= 1);
    float s0[3] = {0.f, 0.f, 0.f}, s1[3] = {0.f, 0.f, 0.f};
#pragma unroll
    for (int mt = 0; mt < 3; ++mt)
#pragma unroll
      for (int nn = 0; nn < 4; ++nn) accC[mt][nn] = (floatx4){0.f, 0.f, 0.f, 0.f};

    const f16* au = &AU[bb][0][0];
    const f16* av = &AV[bb][0][0];
#pragma unroll
    for (int kk = 0; kk < 8; ++kk) {
      const f16* base = (kk < 4) ? au : av;
      const int coff = (((((kk & 3) << 2) + quad)) ^ l16) << 3;
      f16x8 a0 = *(const f16x8*)(base + (0 * 16 + l16) * HID + coff);
      f16x8 a1 = *(const f16x8*)(base + (1 * 16 + l16) * HID + coff);
      f16x8 a2 = *(const f16x8*)(base + (2 * 16 + l16) * HID + coff);
#pragma unroll
      for (int nn = 0; nn < 4; ++nn) {
        accC[0][nn] = __builtin_amdgcn_mfma_f32_16x16x32_f16(bfr[nn][kk], a0, accC[0][nn], 0, 0, 0);
        accC[1][nn] = __builtin_amdgcn_mfma_f32_16x16x32_f16(bfr[nn][kk], a1, accC[1][nn], 0, 0, 0);
        accC[2][nn] = __builtin_amdgcn_mfma_f32_16x16x32_f16(bfr[nn][kk], a2, accC[2][nn], 0, 0, 0);
      }
      // interleaved epilogue of tile t-NB: VALU pipe fills MFMA issue gaps
      if (doEpi) {
        if (kk < 4) {
          piece(accP, 2 * kk, s0, s1);
          piece(accP, 2 * kk + 1, s0, s1);
        } else {
          piece(accP, 8 + (kk - 4), s0, s1);
        }
      }
    }
    if (doEpi) {
#pragma unroll
      for (int mt = 0; mt < 3; ++mt) {
        float a0 = s0[mt] + __shfl_xor(s0[mt], 16); a0 += __shfl_xor(a0, 32);
        float a1 = s1[mt] + __shfl_xor(s1[mt], 16); a1 += __shfl_xor(a1, 32);
        if (quad == 0)
          *(floatx2*)&part[i & 1][wave][mt * 16 + l16][0] = (floatx2){a0, a1};
      }
    }
    bb ^= 1;
  };

  int i = 0;
  for (int t = t0; t < ntiles; t += NB, ++i) {
    if (i & 1) body(accB, accA, t, i);
    else       body(accA, accB, t, i);
  }

  // drain: out-write tile i-2; epilogue + out-write tile i-1.
  if (i >= 1) {
    __syncthreads();
    if (i >= 2 && tid < 2 * NTB) outwrite(t0 + (i - 2) * NB, (i + 1) & 1);
    {
      float s0[3] = {0.f, 0.f, 0.f}, s1[3] = {0.f, 0.f, 0.f};
      if ((i - 1) & 1) {
#pragma unroll
        for (int p = 0; p < 12; ++p) piece(accB, p, s0, s1);
      } else {
#pragma unroll
        for (int p = 0; p < 12; ++p) piece(accA, p, s0, s1);
      }
#pragma unroll
      for (int mt = 0; mt < 3; ++mt) {
        float a0 = s0[mt] + __shfl_xor(s0[mt], 16); a0 += __shfl_xor(a0, 32);
        float a1 = s1[mt] + __shfl_xor(s1[mt], 16); a1 += __shfl_xor(a1, 32);
        if (quad == 0)
          *(floatx2*)&part[i & 1][wave][mt * 16 + l16][0] = (floatx2){a0, a1};
      }
    }
    __syncthreads();
    if (tid < 2 * NTB) outwrite(t0 + (i - 1) * NB, i & 1);
  }
}

// ---------------- tier-2 fallback (bf16, GH materialized) ----------------

__global__ __launch_bounds__(256) void conv_bt_bf(
    const float* __restrict__ W1, short* __restrict__ BT) {
  int idx = blockIdx.x * 256 + threadIdx.x;
  int n = idx >> 7;
  int k = idx & 127;
  float w = (n < N1) ? W1[k * N1 + n] : W1[(k + HID) * N1 + (n - N1)];
  BT[idx] = f2bf(w);
}

__global__ __launch_bounds__(256) void gemm_bf(
    const float* __restrict__ feats, const short* __restrict__ BT,
    short* __restrict__ GH, int n_nodes) {
  const int wave = threadIdx.x >> 6;
  const int lane = threadIdx.x & 63;
  const int quad = lane >> 4;
  const int l16  = lane & 15;
  const int row0 = blockIdx.x * 64 + wave * 16;
  const int n0   = blockIdx.y * 128;
  const int m  = row0 + l16;
  const int mc = (m < n_nodes) ? m : (n_nodes - 1);
  const float* arow = feats + (size_t)mc * HID;
  floatx4 acc[8];
#pragma unroll
  for (int i = 0; i < 8; ++i) acc[i] = (floatx4){0.f, 0.f, 0.f, 0.f};
#pragma unroll
  for (int kk = 0; kk < 4; ++kk) {
    const int kbase = kk * 32 + quad * 8;
    floatx4 a0 = *(const floatx4*)(arow + kbase);
    floatx4 a1 = *(const floatx4*)(arow + kbase + 4);
    short8 af;
#pragma unroll
    for (int j = 0; j < 4; ++j) { float x = a0[j]; af[j] = f2bf(x > 0.f ? x : 0.f); }
#pragma unroll
    for (int j = 0; j < 4; ++j) { float x = a1[j]; af[4 + j] = f2bf(x > 0.f ? x : 0.f); }
    bf16x8 afrag = __builtin_bit_cast(bf16x8, af);
#pragma unroll
    for (int nn = 0; nn < 8; ++nn) {
      const int n = n0 + nn * 16 + l16;
      short8 bs = *(const short8*)(BT + (size_t)n * HID + kbase);
      acc[nn] = __builtin_amdgcn_mfma_f32_16x16x32_bf16(
          afrag, __builtin_bit_cast(bf16x8, bs), acc[nn], 0, 0, 0);
    }
  }
#pragma unroll
  for (int nn = 0; nn < 8; ++nn) {
    const int col = n0 + nn * 16 + l16;
#pragma unroll
    for (int r = 0; r < 4; ++r) {
      const int row = row0 + quad * 4 + r;
      if (row < n_nodes) GH[(size_t)row * NCAT + col] = f2bf(acc[nn][r]);
    }
  }
}

__global__ __launch_bounds__(256) void edge2_bf(
    const short* __restrict__ GH, const int* __restrict__ edges,
    const float* __restrict__ b1, const float* __restrict__ W2,
    const float* __restrict__ b2, float* __restrict__ out, int n_edges) {
  const int wave = threadIdx.x >> 6;
  const int lane = threadIdx.x & 63;
  const int w = blockIdx.x * 4 + wave;
  const int e0 = 2 * w;
  if (e0 >= n_edges) return;
  const bool has1 = (e0 + 1 < n_edges);
  const int j0 = lane * 8;
  const int u0 = edges[e0];
  const int v0 = edges[n_edges + e0];
  const int u1 = has1 ? edges[e0 + 1] : u0;
  const int v1 = has1 ? edges[n_edges + e0 + 1] : v0;
  short8 g0 = *(const short8*)(GH + (size_t)u0 * NCAT + j0);
  short8 h0 = *(const short8*)(GH + (size_t)v0 * NCAT + N1 + j0);
  short8 g1 = *(const short8*)(GH + (size_t)u1 * NCAT + j0);
  short8 h1 = *(const short8*)(GH + (size_t)v1 * NCAT + N1 + j0);
  float bv[8];
  {
    floatx4 t0 = *(const floatx4*)(b1 + j0);
    floatx4 t1 = *(const floatx4*)(b1 + j0 + 4);
#pragma unroll
    for (int j = 0; j < 4; ++j) { bv[j] = t0[j]; bv[4 + j] = t1[j]; }
  }
  float wv[16];
#pragma unroll
  for (int q = 0; q < 4; ++q) {
    floatx4 tt = *(const floatx4*)(W2 + (size_t)j0 * 2 + q * 4);
#pragma unroll
    for (int j = 0; j < 4; ++j) wv[q * 4 + j] = tt[j];
  }
  float s00 = 0.f, s01 = 0.f, s10 = 0.f, s11 = 0.f;
#pragma unroll
  for (int j = 0; j < 8; ++j) {
    float p0 = bf2f(g0[j]) + bf2f(h0[j]) + bv[j];
    p0 = p0 > 0.f ? p0 : 0.f;
    s00 += p0 * wv[2 * j];
    s01 += p0 * wv[2 * j + 1];
    float p1 = bf2f(g1[j]) + bf2f(h1[j]) + bv[j];
    p1 = p1 > 0.f ? p1 : 0.f;
    s10 += p1 * wv[2 * j];
    s11 += p1 * wv[2 * j + 1];
  }
#pragma unroll
  for (int off = 32; off > 0; off >>= 1) {
    s00 += __shfl_down(s00, off, 64);
    s01 += __shfl_down(s01, off, 64);
    s10 += __shfl_down(s10, off, 64);
    s11 += __shfl_down(s11, off, 64);
  }
  if (lane == 0) {
    out[2 * (size_t)e0]     = s00 + b2[0];
    out[2 * (size_t)e0 + 1] = s01 + b2[1];
    if (has1) {
      out[2 * (size_t)e0 + 2] = s10 + b2[0];
      out[2 * (size_t)e0 + 3] = s11 + b2[1];
    }
  }
}

// ---------------- tier-3 fallback: direct fp32 ----------------
__global__ __launch_bounds__(256) void slow_kernel(
    const float* __restrict__ feats, const int* __restrict__ edges,
    const float* __restrict__ W1, const float* __restrict__ b1,
    const float* __restrict__ W2, const float* __restrict__ b2,
    float* __restrict__ out, int n_edges) {
  const int wave = threadIdx.x >> 6;
  const int lane = threadIdx.x & 63;
  const int edge = blockIdx.x * 4 + wave;
  if (edge >= n_edges) return;
  const int u = edges[edge];
  const int v = edges[n_edges + edge];
  float f[4];
  f[0] = feats[(size_t)u * HID + lane];
  f[1] = feats[(size_t)u * HID + 64 + lane];
  f[2] = feats[(size_t)v * HID + lane];
  f[3] = feats[(size_t)v * HID + 64 + lane];
#pragma unroll
  for (int i = 0; i < 4; ++i) f[i] = f[i] > 0.f ? f[i] : 0.f;
  const int j0 = lane * 8;
  float acc[8];
#pragma unroll
  for (int j = 0; j < 8; ++j) acc[j] = 0.f;
#pragma unroll
  for (int seg = 0; seg < 4; ++seg) {
    float fs = f[seg];
    for (int k2 = 0; k2 < 64; ++k2) {
      float fk = __shfl(fs, k2, 64);
      const float* wr = W1 + (size_t)(seg * 64 + k2) * N1 + j0;
#pragma unroll
      for (int j = 0; j < 8; ++j) acc[j] += fk * wr[j];
    }
  }
  float s0 = 0.f, s1 = 0.f;
#pragma unroll
  for (int j = 0; j < 8; ++j) {
    float p = acc[j] + b1[j0 + j];
    p = p > 0.f ? p : 0.f;
    s0 += p * W2[(size_t)(j0 + j) * 2];
    s1 += p * W2[(size_t)(j0 + j) * 2 + 1];
  }
#pragma unroll
  for (int off = 32; off > 0; off >>= 1) {
    s0 += __shfl_down(s0, off, 64);
    s1 += __shfl_down(s1, off, 64);
  }
  if (lane == 0) {
    out[2 * (size_t)edge]     = s0 + b2[0];
    out[2 * (size_t)edge + 1] = s1 + b2[1];
  }
}

extern "C" void kernel_launch(void* const* d_in, const int* in_sizes, int n_in,
                              void* d_out, int out_size, void* d_ws, size_t ws_size,
                              hipStream_t stream) {
  const float* feats = (const float*)d_in[0];
  const int*   edges = (const int*)d_in[1];
  const float* W1    = (const float*)d_in[2];
  const float* b1    = (const float*)d_in[3];
  const float* W2    = (const float*)d_in[4];
  const float* b2    = (const float*)d_in[5];
  float* out = (float*)d_out;

  const int n_nodes = in_sizes[0] / HID;
  const int n_edges = in_sizes[1] / 2;

  const size_t bt2_bytes = (size_t)N1 * 256 * 2;       // 256 KiB (W1^T f16)
  const size_t a_bytes   = (size_t)n_nodes * HID * 2;  // ~25.6 MB (relu'd feats f16)

  const size_t bt_bytes = (size_t)NCAT * HID * 2;      // tier-2 layout
  const size_t gh_bytes = (size_t)n_nodes * NCAT * 2;

  if (ws_size >= bt2_bytes + a_bytes) {
    f16* BT2 = (f16*)d_ws;
    f16* A   = (f16*)((char*)d_ws + bt2_bytes);
    const int total4 = n_nodes * (HID / 4);
    const int prep_total = total4 + N1 * 256;
    prep_all<<<(prep_total + 255) / 256, 256, 0, stream>>>(feats, W1, A, BT2, total4);
    const int ntiles = (n_edges + NTB - 1) / NTB;
    const int nb = ntiles < 256 ? ntiles : 256;
    fused_kernel<<<nb, 512, 0, stream>>>(A, BT2, b1, W2, b2, edges, out, n_edges, ntiles);
  } else if (ws_size >= bt_bytes + gh_bytes) {
    short* BT = (short*)d_ws;
    short* GH = (short*)((char*)d_ws + bt_bytes);
    conv_bt_bf<<<(NCAT * HID) / 256, 256, 0, stream>>>(W1, BT);
    dim3 grid((n_nodes + 63) / 64, NCAT / 128);
    gemm_bf<<<grid, 256, 0, stream>>>(feats, BT, GH, n_nodes);
    edge2_bf<<<((n_edges + 1) / 2 + 3) / 4, 256, 0, stream>>>(GH, edges, b1, W2, b2, out, n_edges);
  } else {
    slow_kernel<<<(n_edges + 3) / 4, 256, 0, stream>>>(feats, edges, W1, b1, W2, b2, out, n_edges);
  }
}

// Round 3
// 224.461 us; speedup vs baseline: 4.1292x; 4.1292x over previous
//
#include <hip/hip_runtime.h>
#include <stdint.h>

#define HID  128
#define N1   512
#define NCAT 1024
#define NTB  48      // edges per tile in the fused kernel

typedef _Float16 f16;
typedef __attribute__((ext_vector_type(8))) _Float16 f16x8;
typedef __attribute__((ext_vector_type(4))) _Float16 f16x4;
typedef __attribute__((ext_vector_type(2))) _Float16 f16x2;
typedef __attribute__((ext_vector_type(8))) short   short8;
typedef __attribute__((ext_vector_type(4))) float   floatx4;
typedef __attribute__((ext_vector_type(2))) float   floatx2;
typedef __attribute__((ext_vector_type(8))) __bf16  bf16x8;

static __device__ __forceinline__ short f2bf(float x) {
  uint32_t u = __builtin_bit_cast(uint32_t, x);
  uint32_t r = (u + 0x7FFFu + ((u >> 16) & 1u)) >> 16;
  return (short)r;
}
static __device__ __forceinline__ float bf2f(short s) {
  uint32_t u = ((uint32_t)(uint16_t)s) << 16;
  return __builtin_bit_cast(float, u);
}
static __device__ __forceinline__ f16x2 pkrtz(float a, float b) {
  return __builtin_bit_cast(f16x2, __builtin_amdgcn_cvt_pkrtz(a, b));
}
typedef __fp16 __attribute__((ext_vector_type(2))) fp16v2;
static __device__ __forceinline__ float fdot2(f16x2 a, f16x2 b, float c) {
#if __has_builtin(__builtin_amdgcn_fdot2)
  return __builtin_amdgcn_fdot2(__builtin_bit_cast(fp16v2, a),
                                __builtin_bit_cast(fp16v2, b), c, false);
#else
  return c + (float)a[0] * (float)b[0] + (float)a[1] * (float)b[1];
#endif
}

// async global->LDS, 16B per lane. Global source address is per-lane
// (scatter/gather OK); LDS dest is wave-uniform base + lane*16.
static __device__ __forceinline__ void gload16(const f16* g, f16* l) {
  __builtin_amdgcn_global_load_lds(
      (const __attribute__((address_space(1))) unsigned int*)g,
      (__attribute__((address_space(3))) unsigned int*)l, 16, 0, 0);
}

// ---------------- tier-1 (fused fp16 MFMA) ----------------

// prep: A' = relu(feats) as f16 (n_nodes,128); BT2[n][k] = W1[k][n] f16,
// n in [0,512), k in [0,256) (K = concat dim: k<128 -> u-features).
__global__ __launch_bounds__(256) void prep_all(
    const float* __restrict__ feats, const float* __restrict__ W1,
    f16* __restrict__ A, f16* __restrict__ BT2, int total4) {
  int idx = blockIdx.x * 256 + threadIdx.x;
  if (idx < total4) {
    floatx4 f = *(const floatx4*)(feats + (size_t)idx * 4);
    f16x4 o;
#pragma unroll
    for (int j = 0; j < 4; ++j) o[j] = (f16)fmaxf(f[j], 0.f);
    *(f16x4*)(A + (size_t)idx * 4) = o;
    return;
  }
  int w = idx - total4;
  if (w < N1 * 256) {
    int n = w >> 8;
    int k = w & 255;
    BT2[w] = (f16)W1[k * N1 + n];
  }
}

// One epilogue "piece": bias+relu (packed f32) + f16 dot with W2 pairs.
// EACC[NN] holds hidden[m][nb..nb+3] f32; accumulates the two outputs.
#define PIECE(EACC, NN, S0, S1)                                            \
  {                                                                        \
    const int nb_ = n0w + (NN) * 16 + (quad << 2);                         \
    const floatx4 bv_ = *(const floatx4*)&b1s[nb_];                        \
    const f16x4 wq0_ = *(const f16x4*)&w2h0[nb_ >> 1];                     \
    const f16x4 wq1_ = *(const f16x4*)&w2h1[nb_ >> 1];                     \
    floatx2 a01_ = {EACC[NN][0] + bv_[0], EACC[NN][1] + bv_[1]};           \
    floatx2 a23_ = {EACC[NN][2] + bv_[2], EACC[NN][3] + bv_[3]};           \
    a01_ = __builtin_elementwise_max(a01_, (floatx2){0.f, 0.f});           \
    a23_ = __builtin_elementwise_max(a23_, (floatx2){0.f, 0.f});           \
    f16x2 z01_ = pkrtz(a01_[0], a01_[1]);                                  \
    f16x2 z23_ = pkrtz(a23_[0], a23_[1]);                                  \
    S0 = fdot2(z01_, (f16x2){wq0_[0], wq0_[1]}, S0);                       \
    S0 = fdot2(z23_, (f16x2){wq0_[2], wq0_[3]}, S0);                       \
    S1 = fdot2(z01_, (f16x2){wq1_[0], wq1_[1]}, S1);                       \
    S1 = fdot2(z23_, (f16x2){wq1_[2], wq1_[3]}, S1);                       \
  }

// 32-MFMA burst for row-block MROW; optionally interleaves the epilogue
// slice of EACC (a COMPLETED accumulator) into the MFMA stream. VALU/DS
// epilogue ops fill MFMA issue gaps (separate pipes, m114). No extra
// accumulator state: the carried slice (prev tile's acc2) is read before
// acc2's own burst re-zeroes it.
#define BURST(MACC, MROW, EPI, EACC, ESLOT, EMT)                           \
  {                                                                        \
    _Pragma("unroll") for (int nn = 0; nn < 4; ++nn)                       \
        MACC[nn] = (floatx4){0.f, 0.f, 0.f, 0.f};                          \
    float es0_ = 0.f, es1_ = 0.f;                                          \
    _Pragma("unroll") for (int kk = 0; kk < 8; ++kk) {                     \
      const f16* base_ = (kk < 4) ? au : av;                               \
      const int coff_ = (((((kk & 3) << 2) + quad)) ^ l16) << 3;           \
      f16x8 af_ = *(const f16x8*)(base_ + ((MROW) * 16 + l16) * HID + coff_); \
      _Pragma("unroll") for (int nn = 0; nn < 4; ++nn)                     \
        MACC[nn] = __builtin_amdgcn_mfma_f32_16x16x32_f16(                 \
            bfr[nn][kk], af_, MACC[nn], 0, 0, 0);                          \
      if (EPI) {                                                           \
        if (kk < 4) { PIECE(EACC, kk, es0_, es1_); }                       \
        else if (kk == 4) { es0_ += __shfl_xor(es0_, 16);                  \
                            es1_ += __shfl_xor(es1_, 16); }                \
        else if (kk == 5) { es0_ += __shfl_xor(es0_, 32);                  \
                            es1_ += __shfl_xor(es1_, 32); }                \
        else if (kk == 6) { if (quad == 0)                                 \
            *(floatx2*)&part[ESLOT][wave][(EMT) * 16 + l16][0] =           \
                (floatx2){es0_, es1_}; }                                   \
      }                                                                    \
    }                                                                      \
  }

__global__ __launch_bounds__(512, 2) void fused_kernel(
    const f16* __restrict__ A,      // (n_nodes,128) relu'd f16
    const f16* __restrict__ BT2,    // (512,256) f16 = W1^T
    const float* __restrict__ b1,   // (512,)
    const float* __restrict__ W2,   // (512,2)
    const float* __restrict__ b2,   // (2,)
    const int* __restrict__ edges,  // (2, n_edges) int32
    float* __restrict__ out,        // (n_edges,2)
    int n_edges, int ntiles) {
  __shared__ f16 AU[2][NTB][HID];        // 24 KB  (u half, K 0..127)
  __shared__ f16 AV[2][NTB][HID];        // 24 KB  (v half, K 128..255)
  __shared__ float part[3][8][NTB][2];   // 9 KB   cross-wave partials (3-deep)
  __shared__ float b1s[N1];              // 2 KB
  __shared__ f16x2 w2h0[N1 / 2];         // 1 KB  (W2[n][0],W2[n+1][0]) f16 pairs
  __shared__ f16x2 w2h1[N1 / 2];         // 1 KB

  const int tid  = threadIdx.x;
  const int wave = tid >> 6;
  const int lane = tid & 63;
  const int quad = lane >> 4;
  const int l16  = lane & 15;
  const int n0w  = wave << 6;            // this wave's 64-col N slice

  if (tid < N1) b1s[tid] = b1[tid];
  if (tid < N1 / 2) {
    floatx4 w = *(const floatx4*)(W2 + 4 * tid);   // rows 2t,2t+1 of (512,2)
    w2h0[tid] = pkrtz(w[0], w[2]);
    w2h1[tid] = pkrtz(w[1], w[3]);
  }
  const float b2v0 = b2[0], b2v1 = b2[1];

  // Persistent B fragments (128 VGPR): row <-> l16, k <-> quad*8 + kk*32.
  f16x8 bfr[4][8];
#pragma unroll
  for (int nn = 0; nn < 4; ++nn) {
    const f16* bp = BT2 + (size_t)(n0w + nn * 16 + l16) * 256 + quad * 8;
#pragma unroll
    for (int kk = 0; kk < 8; ++kk) bfr[nn][kk] = *(const f16x8*)(bp + kk * 32);
  }

  // Gather geometry: 24 calls of 4 rows (64 lanes x 16B = 1KB each);
  // wave w issues calls j = 3w..3w+2.  j<12 -> AU rows 4j.., else AV.
  const int j0   = wave * 3;
  const int rsub = lane >> 4;

  int idr[3];
  auto load_idx = [&](int t) {
#pragma unroll
    for (int c = 0; c < 3; ++c) {
      int j = j0 + c;
      int side = (j >= 12) ? 1 : 0;
      int r = ((j - side * 12) << 2) + rsub;
      int e = t * NTB + r;
      if (e >= n_edges) e = n_edges - 1;
      idr[c] = edges[side * n_edges + e];
    }
  };
  // XOR-swizzle via pre-swizzled global source (m173); LDS dest linear.
  auto issue_gather = [&](int b) {
#pragma unroll
    for (int c = 0; c < 3; ++c) {
      int j = j0 + c;
      int side = (j >= 12) ? 1 : 0;
      int r0 = (j - side * 12) << 2;
      int r  = r0 + rsub;
      const f16* src = A + ((size_t)idr[c] << 7) + (((lane & 15) ^ (r & 15)) << 3);
      f16* dst = side ? &AV[b][r0][0] : &AU[b][r0][0];
      gload16(src, dst);
    }
  };

  auto outwrite = [&](int tt, int ps) {
    const int m = tid >> 1, jj = tid & 1;
    float s = part[ps][0][m][jj] + part[ps][1][m][jj] + part[ps][2][m][jj] +
              part[ps][3][m][jj] + part[ps][4][m][jj] + part[ps][5][m][jj] +
              part[ps][6][m][jj] + part[ps][7][m][jj];
    const int e = tt * NTB + m;
    if (e < n_edges) out[2 * (size_t)e + jj] = s + (jj ? b2v1 : b2v0);
  };

  const int NB = gridDim.x;
  const int t0 = blockIdx.x;
  int bb = 0;

  if (t0 < ntiles) {
    load_idx(t0);
    issue_gather(0);
    load_idx(t0 + NB);
  }

  floatx4 acc0[4], acc1[4], acc2[4];

  int i = 0;
  for (int t = t0; t < ntiles; t += NB, ++i) {
    // Single barrier per tile: gathers for t complete; part[(i-1)%3] and
    // part[(i-2)%3] writes from earlier tiles are now block-visible.
    __syncthreads();

    if (t + NB < ntiles) {
      issue_gather(bb ^ 1);          // tile t+NB flies under compute
      load_idx(t + 2 * NB);
    }
    if (i >= 2 && tid < 2 * NTB) outwrite(t - 2 * NB, (i - 2) % 3);

    const f16* au = &AU[bb][0][0];
    const f16* av = &AV[bb][0][0];
    const int slotP = (i + 2) % 3;   // == (i-1)%3 for i>=1
    const int slotC = i % 3;

    // mt=0 burst carries prev tile's acc2 epilogue (slice mt=2).
    if (i >= 1) {
      BURST(acc0, 0, 1, acc2, slotP, 2);
    } else {
      BURST(acc0, 0, 0, acc0, 0, 0);
    }
    // mt=1 burst carries this tile's acc0 epilogue; mt=2 carries acc1.
    BURST(acc1, 1, 1, acc0, slotC, 0);
    BURST(acc2, 2, 1, acc1, slotC, 1);
    bb ^= 1;
  }

  // Drain: out-write tile i-2, finish acc2 of tile i-1, out-write tile i-1.
  if (i >= 1) {
    __syncthreads();
    if (i >= 2 && tid < 2 * NTB) outwrite(t0 + (i - 2) * NB, (i - 2) % 3);
    {
      float es0_ = 0.f, es1_ = 0.f;
      PIECE(acc2, 0, es0_, es1_);
      PIECE(acc2, 1, es0_, es1_);
      PIECE(acc2, 2, es0_, es1_);
      PIECE(acc2, 3, es0_, es1_);
      es0_ += __shfl_xor(es0_, 16); es1_ += __shfl_xor(es1_, 16);
      es0_ += __shfl_xor(es0_, 32); es1_ += __shfl_xor(es1_, 32);
      if (quad == 0)
        *(floatx2*)&part[(i + 2) % 3][wave][2 * 16 + l16][0] = (floatx2){es0_, es1_};
    }
    __syncthreads();
    if (tid < 2 * NTB) outwrite(t0 + (i - 1) * NB, (i + 2) % 3);
  }
}

// ---------------- tier-2 fallback (bf16, GH materialized) ----------------

__global__ __launch_bounds__(256) void conv_bt_bf(
    const float* __restrict__ W1, short* __restrict__ BT) {
  int idx = blockIdx.x * 256 + threadIdx.x;
  int n = idx >> 7;
  int k = idx & 127;
  float w = (n < N1) ? W1[k * N1 + n] : W1[(k + HID) * N1 + (n - N1)];
  BT[idx] = f2bf(w);
}

__global__ __launch_bounds__(256) void gemm_bf(
    const float* __restrict__ feats, const short* __restrict__ BT,
    short* __restrict__ GH, int n_nodes) {
  const int wave = threadIdx.x >> 6;
  const int lane = threadIdx.x & 63;
  const int quad = lane >> 4;
  const int l16  = lane & 15;
  const int row0 = blockIdx.x * 64 + wave * 16;
  const int n0   = blockIdx.y * 128;
  const int m  = row0 + l16;
  const int mc = (m < n_nodes) ? m : (n_nodes - 1);
  const float* arow = feats + (size_t)mc * HID;
  floatx4 acc[8];
#pragma unroll
  for (int i = 0; i < 8; ++i) acc[i] = (floatx4){0.f, 0.f, 0.f, 0.f};
#pragma unroll
  for (int kk = 0; kk < 4; ++kk) {
    const int kbase = kk * 32 + quad * 8;
    floatx4 a0 = *(const floatx4*)(arow + kbase);
    floatx4 a1 = *(const floatx4*)(arow + kbase + 4);
    short8 af;
#pragma unroll
    for (int j = 0; j < 4; ++j) { float x = a0[j]; af[j] = f2bf(x > 0.f ? x : 0.f); }
#pragma unroll
    for (int j = 0; j < 4; ++j) { float x = a1[j]; af[4 + j] = f2bf(x > 0.f ? x : 0.f); }
    bf16x8 afrag = __builtin_bit_cast(bf16x8, af);
#pragma unroll
    for (int nn = 0; nn < 8; ++nn) {
      const int n = n0 + nn * 16 + l16;
      short8 bs = *(const short8*)(BT + (size_t)n * HID + kbase);
      acc[nn] = __builtin_amdgcn_mfma_f32_16x16x32_bf16(
          afrag, __builtin_bit_cast(bf16x8, bs), acc[nn], 0, 0, 0);
    }
  }
#pragma unroll
  for (int nn = 0; nn < 8; ++nn) {
    const int col = n0 + nn * 16 + l16;
#pragma unroll
    for (int r = 0; r < 4; ++r) {
      const int row = row0 + quad * 4 + r;
      if (row < n_nodes) GH[(size_t)row * NCAT + col] = f2bf(acc[nn][r]);
    }
  }
}

__global__ __launch_bounds__(256) void edge2_bf(
    const short* __restrict__ GH, const int* __restrict__ edges,
    const float* __restrict__ b1, const float* __restrict__ W2,
    const float* __restrict__ b2, float* __restrict__ out, int n_edges) {
  const int wave = threadIdx.x >> 6;
  const int lane = threadIdx.x & 63;
  const int w = blockIdx.x * 4 + wave;
  const int e0 = 2 * w;
  if (e0 >= n_edges) return;
  const bool has1 = (e0 + 1 < n_edges);
  const int j0 = lane * 8;
  const int u0 = edges[e0];
  const int v0 = edges[n_edges + e0];
  const int u1 = has1 ? edges[e0 + 1] : u0;
  const int v1 = has1 ? edges[n_edges + e0 + 1] : v0;
  short8 g0 = *(const short8*)(GH + (size_t)u0 * NCAT + j0);
  short8 h0 = *(const short8*)(GH + (size_t)v0 * NCAT + N1 + j0);
  short8 g1 = *(const short8*)(GH + (size_t)u1 * NCAT + j0);
  short8 h1 = *(const short8*)(GH + (size_t)v1 * NCAT + N1 + j0);
  float bv[8];
  {
    floatx4 t0 = *(const floatx4*)(b1 + j0);
    floatx4 t1 = *(const floatx4*)(b1 + j0 + 4);
#pragma unroll
    for (int j = 0; j < 4; ++j) { bv[j] = t0[j]; bv[4 + j] = t1[j]; }
  }
  float wv[16];
#pragma unroll
  for (int q = 0; q < 4; ++q) {
    floatx4 tt = *(const floatx4*)(W2 + (size_t)j0 * 2 + q * 4);
#pragma unroll
    for (int j = 0; j < 4; ++j) wv[q * 4 + j] = tt[j];
  }
  float s00 = 0.f, s01 = 0.f, s10 = 0.f, s11 = 0.f;
#pragma unroll
  for (int j = 0; j < 8; ++j) {
    float p0 = bf2f(g0[j]) + bf2f(h0[j]) + bv[j];
    p0 = p0 > 0.f ? p0 : 0.f;
    s00 += p0 * wv[2 * j];
    s01 += p0 * wv[2 * j + 1];
    float p1 = bf2f(g1[j]) + bf2f(h1[j]) + bv[j];
    p1 = p1 > 0.f ? p1 : 0.f;
    s10 += p1 * wv[2 * j];
    s11 += p1 * wv[2 * j + 1];
  }
#pragma unroll
  for (int off = 32; off > 0; off >>= 1) {
    s00 += __shfl_down(s00, off, 64);
    s01 += __shfl_down(s01, off, 64);
    s10 += __shfl_down(s10, off, 64);
    s11 += __shfl_down(s11, off, 64);
  }
  if (lane == 0) {
    out[2 * (size_t)e0]     = s00 + b2[0];
    out[2 * (size_t)e0 + 1] = s01 + b2[1];
    if (has1) {
      out[2 * (size_t)e0 + 2] = s10 + b2[0];
      out[2 * (size_t)e0 + 3] = s11 + b2[1];
    }
  }
}

// ---------------- tier-3 fallback: direct fp32 ----------------
__global__ __launch_bounds__(256) void slow_kernel(
    const float* __restrict__ feats, const int* __restrict__ edges,
    const float* __restrict__ W1, const float* __restrict__ b1,
    const float* __restrict__ W2, const float* __restrict__ b2,
    float* __restrict__ out, int n_edges) {
  const int wave = threadIdx.x >> 6;
  const int lane = threadIdx.x & 63;
  const int edge = blockIdx.x * 4 + wave;
  if (edge >= n_edges) return;
  const int u = edges[edge];
  const int v = edges[n_edges + edge];
  float f[4];
  f[0] = feats[(size_t)u * HID + lane];
  f[1] = feats[(size_t)u * HID + 64 + lane];
  f[2] = feats[(size_t)v * HID + lane];
  f[3] = feats[(size_t)v * HID + 64 + lane];
#pragma unroll
  for (int i = 0; i < 4; ++i) f[i] = f[i] > 0.f ? f[i] : 0.f;
  const int j0 = lane * 8;
  float acc[8];
#pragma unroll
  for (int j = 0; j < 8; ++j) acc[j] = 0.f;
#pragma unroll
  for (int seg = 0; seg < 4; ++seg) {
    float fs = f[seg];
    for (int k2 = 0; k2 < 64; ++k2) {
      float fk = __shfl(fs, k2, 64);
      const float* wr = W1 + (size_t)(seg * 64 + k2) * N1 + j0;
#pragma unroll
      for (int j = 0; j < 8; ++j) acc[j] += fk * wr[j];
    }
  }
  float s0 = 0.f, s1 = 0.f;
#pragma unroll
  for (int j = 0; j < 8; ++j) {
    float p = acc[j] + b1[j0 + j];
    p = p > 0.f ? p : 0.f;
    s0 += p * W2[(size_t)(j0 + j) * 2];
    s1 += p * W2[(size_t)(j0 + j) * 2 + 1];
  }
#pragma unroll
  for (int off = 32; off > 0; off >>= 1) {
    s0 += __shfl_down(s0, off, 64);
    s1 += __shfl_down(s1, off, 64);
  }
  if (lane == 0) {
    out[2 * (size_t)edge]     = s0 + b2[0];
    out[2 * (size_t)edge + 1] = s1 + b2[1];
  }
}

extern "C" void kernel_launch(void* const* d_in, const int* in_sizes, int n_in,
                              void* d_out, int out_size, void* d_ws, size_t ws_size,
                              hipStream_t stream) {
  const float* feats = (const float*)d_in[0];
  const int*   edges = (const int*)d_in[1];
  const float* W1    = (const float*)d_in[2];
  const float* b1    = (const float*)d_in[3];
  const float* W2    = (const float*)d_in[4];
  const float* b2    = (const float*)d_in[5];
  float* out = (float*)d_out;

  const int n_nodes = in_sizes[0] / HID;
  const int n_edges = in_sizes[1] / 2;

  const size_t bt2_bytes = (size_t)N1 * 256 * 2;       // 256 KiB (W1^T f16)
  const size_t a_bytes   = (size_t)n_nodes * HID * 2;  // ~25.6 MB (relu'd feats f16)

  const size_t bt_bytes = (size_t)NCAT * HID * 2;      // tier-2 layout
  const size_t gh_bytes = (size_t)n_nodes * NCAT * 2;

  if (ws_size >= bt2_bytes + a_bytes) {
    f16* BT2 = (f16*)d_ws;
    f16* A   = (f16*)((char*)d_ws + bt2_bytes);
    const int total4 = n_nodes * (HID / 4);
    const int prep_total = total4 + N1 * 256;
    prep_all<<<(prep_total + 255) / 256, 256, 0, stream>>>(feats, W1, A, BT2, total4);
    const int ntiles = (n_edges + NTB - 1) / NTB;
    const int nb = ntiles < 256 ? ntiles : 256;
    fused_kernel<<<nb, 512, 0, stream>>>(A, BT2, b1, W2, b2, edges, out, n_edges, ntiles);
  } else if (ws_size >= bt_bytes + gh_bytes) {
    short* BT = (short*)d_ws;
    short* GH = (short*)((char*)d_ws + bt_bytes);
    conv_bt_bf<<<(NCAT * HID) / 256, 256, 0, stream>>>(W1, BT);
    dim3 grid((n_nodes + 63) / 64, NCAT / 128);
    gemm_bf<<<grid, 256, 0, stream>>>(feats, BT, GH, n_nodes);
    edge2_bf<<<((n_edges + 1) / 2 + 3) / 4, 256, 0, stream>>>(GH, edges, b1, W2, b2, out, n_edges);
  } else {
    slow_kernel<<<(n_edges + 3) / 4, 256, 0, stream>>>(feats, edges, W1, b1, W2, b2, out, n_edges);
  }
}